// Round 4
// baseline (696.169 us; speedup 1.0000x reference)
//
#include <hip/hip_runtime.h>

// NSDE pricer, R7: 8-wave (512-thr) blocks -> guaranteed 2 waves/SIMD.
// R6b post-mortem: W1-in-LDS fixed the spill (FETCH 1.68GB -> 0.5MB) but
// occupancy stayed 11.7% (1 wave/SIMD): 2 blocks/CU would need 2x37.9KB LDS
// > 64KB effective scheduling budget (R5 with 5KB LDS DID get 2 blocks/CU).
// Fix: one 512-thread block = 8 waves = 2 paths shares a single w1f copy;
// only 1 block/CU needed for 8 waves/CU = 2/SIMD. __launch_bounds__(512)
// forces VGPR<=256 so residency is guaranteed. Step-loop code identical to
// R6b (pure geometry A/B).
// Wave = 16 rows (one 16x16 M-tile). Layer2 (64x64) per net = 8x
// mfma_f32_16x16x32_bf16, W1 as bf16 B-frags in LDS (lane-contiguous
// ds_read_b128). Layer1/3 + tanh in fp32 VALU. S,V in per-wave LDS slices ->
// no __syncthreads in the 32-step loop.

#define N_PATHS 512
#define N_STEPS 32
#define B_OPTS  64
#define HID     64

typedef __attribute__((ext_vector_type(8))) short bf16x8;   // 8 bf16 (4 VGPRs)
typedef __attribute__((ext_vector_type(4))) float f32x4;

__device__ __forceinline__ float fast_tanh(float x) {
    // tanh(x) = 1 - 2/(e^{2x}+1); exp2-based, correct saturation at +/-inf.
    float u = __builtin_amdgcn_exp2f(x * 2.8853900817779268f);
    float r = __builtin_amdgcn_rcpf(u + 1.0f);
    return fmaf(-2.0f, r, 1.0f);
}

__device__ __forceinline__ short f2bf(float f) {            // fp32 -> bf16 RNE
    union { float f; unsigned u; } c; c.f = f;
    unsigned u = c.u + 0x7FFFu + ((c.u >> 16) & 1u);
    return (short)(u >> 16);
}

__device__ __forceinline__ float select4(float a0, float a1, float a2, float a3, int idx) {
    float lo = (idx & 1) ? a1 : a0;
    float hi = (idx & 1) ? a3 : a2;
    return (idx & 2) ? hi : lo;
}

// Two nets of one phase: layer1 (VALU, A-layout), layer2 (MFMA, W1 frags from
// LDS), layer3+tanh. fout[nn][reg] = f for row (4q + reg) of this wave's
// 16-row tile, all lanes valid after the shfl reduce.
__device__ __forceinline__ void mlp_pair(
    int base, int q, int nh,
    float Sa, float Va, float tA,
    const float4* __restrict__ w0t4,            // LDS, [4][72] swizzled
    const uint4* __restrict__ w1p,              // LDS frags, pre-offset by lane
    const float (&b1v)[4][4], const float (&w2v)[4][4], const float (&b2s)[4],
    float (&fout)[2][4])
{
#pragma unroll
    for (int nn = 0; nn < 2; ++nn) {
        const int net = base + nn;
        // ---- layer1 in A-fragment layout: lane holds h1[row=nh][k=32kh+8q+j]
        bf16x8 afr[2];                           // [kh]
#pragma unroll
        for (int kh = 0; kh < 2; ++kh) {
#pragma unroll
            for (int j = 0; j < 8; ++j) {
                const int kk = kh * 32 + q * 8 + j;
                const float4 w = w0t4[net * 72 + kk + (kk >> 3)]; // bank-swizzled
                float a = fmaf(Sa, w.x, fmaf(Va, w.y, fmaf(tA, w.z, w.w)));
                afr[kh][j] = f2bf(fast_tanh(a));
            }
        }
        // ---- layer2: 1 M-tile x 4 N-tiles x 2 K-halves, W1 frags via
        // ds_read_b128 (lane-contiguous, conflict-free, immediate offsets)
        f32x4 C[4];
#pragma unroll
        for (int nt = 0; nt < 4; ++nt) {
            const bf16x8 bf0 = __builtin_bit_cast(bf16x8, w1p[((net * 4 + nt) * 2 + 0) * 64]);
            const bf16x8 bf1 = __builtin_bit_cast(bf16x8, w1p[((net * 4 + nt) * 2 + 1) * 64]);
            f32x4 c = {0.0f, 0.0f, 0.0f, 0.0f};
            c = __builtin_amdgcn_mfma_f32_16x16x32_bf16(afr[0], bf0, c, 0, 0, 0);
            c = __builtin_amdgcn_mfma_f32_16x16x32_bf16(afr[1], bf1, c, 0, 0, 0);
            C[nt] = c;
        }
        // ---- layer3: tanh, dot with W2 over nt, reduce over 16 C-columns
#pragma unroll
        for (int reg = 0; reg < 4; ++reg) {
            float s = 0.0f;
#pragma unroll
            for (int nt = 0; nt < 4; ++nt)
                s = fmaf(fast_tanh(C[nt][reg] + b1v[net][nt]), w2v[net][nt], s);
            s += __shfl_xor(s, 1);
            s += __shfl_xor(s, 2);
            s += __shfl_xor(s, 4);
            s += __shfl_xor(s, 8);
            fout[nn][reg] = s + b2s[net];
        }
    }
}

__global__ __launch_bounds__(512) void nsde_kernel(
    const float* __restrict__ S0p, const float* __restrict__ Kp,
    const float* __restrict__ Tp,  const float* __restrict__ rfp,
    const float* __restrict__ Z1,  const float* __restrict__ Z2,
    const float* __restrict__ W0,  const float* __restrict__ b0,
    const float* __restrict__ W1,  const float* __restrict__ b1,
    const float* __restrict__ W2,  const float* __restrict__ b2,
    float* __restrict__ out, float* __restrict__ ws, int use_ws)
{
    const int tid  = threadIdx.x;
    const int wave = tid >> 6;                      // 0..7
    const int lane = tid & 63;
    const int q    = lane >> 4;
    const int nh   = lane & 15;
    const int pl   = wave >> 2;                     // path-local 0/1
    const int path = blockIdx.x * 2 + pl;           // uniform per wave

    __shared__ float  S_lds[128], V_lds[128];       // [pl*64 + row]
    __shared__ float4 w0t4[4 * 72];                 // swizzled (w_S,w_V,w_t, b0+rf*w_rf)
    __shared__ uint4  w1f[2048];                    // W1 bf16 frags, 32 KB
                                                    // [net][nt][kh] x [q][nh]

    const float rf = rfp[0];

    // ---- one-time staging: W0 columns ----
    if (tid < 256) {
        const int net = tid >> 6, kk = tid & 63;
        const float wsv = W0[net * 256 + 0 * 64 + kk];
        const float wvv = W0[net * 256 + 1 * 64 + kk];
        const float wrv = W0[net * 256 + 2 * 64 + kk];
        const float wtv = W0[net * 256 + 3 * 64 + kk];
        w0t4[net * 72 + kk + (kk >> 3)] =
            make_float4(wsv, wvv, wtv, fmaf(rf, wrv, b0[net * 64 + kk]));
    }
    if (tid < 128) { S_lds[tid] = S0p[tid & 63]; V_lds[tid] = 0.2f; }

    // ---- one-time staging: W1 -> LDS bf16 B-fragments ----
    // frag f: nh=f&15, q=(f>>4)&3, kh=(f>>6)&1, nt=(f>>7)&3, net=(f>>9)&3
    // holds B[k=32kh+8q+j][n=16nt+nh], j=0..7 packed (16 B).
#pragma unroll
    for (int it = 0; it < 4; ++it) {
        const int f   = it * 512 + tid;
        const int fnh = f & 15;
        const int fq  = (f >> 4) & 3;
        const int fkh = (f >> 6) & 1;
        const int fnt = (f >> 7) & 3;
        const int fnet= (f >> 9) & 3;
        const float* wp = W1 + fnet * 4096 + (fkh * 32 + fq * 8) * 64 + fnt * 16 + fnh;
        bf16x8 fr;
#pragma unroll
        for (int j = 0; j < 8; ++j) fr[j] = f2bf(wp[j * 64]);
        w1f[f] = __builtin_bit_cast(uint4, fr);
    }

    // ---- per-lane constants ----
    const int oA = pl * 64 + (wave & 3) * 16 + nh;              // A-layout row
    const int oW = pl * 64 + (wave & 3) * 16 + 4 * q + (nh & 3);// writer row
    const float dta = Tp[oA & 63] * (1.0f / N_STEPS);
    const float dtw = Tp[oW & 63] * (1.0f / N_STEPS);
    const float sqw = sqrtf(dtw);

    float b1v[4][4], w2v[4][4], b2s[4];
#pragma unroll
    for (int net = 0; net < 4; ++net) {
        b2s[net] = b2[net];
#pragma unroll
        for (int nt = 0; nt < 4; ++nt) {
            b1v[net][nt] = b1[net * 64 + nt * 16 + nh];
            w2v[net][nt] = W2[net * 64 + nt * 16 + nh];
        }
    }

    __syncthreads();

    const uint4* __restrict__ w1p = &w1f[q * 16 + nh];  // lane-contiguous base
    const float* __restrict__ z1p = Z1 + path * N_STEPS;
    const float* __restrict__ z2p = Z2 + path * N_STEPS;

    for (int step = 0; step < N_STEPS; ++step) {
        const float z1 = z1p[step];
        const float z2 = z2p[step];
        const float tA = dta * (float)step;

        // ---- phase 1: nets 0,1 on (S, V, rf, t) ----
        float Sa = S_lds[oA];
        const float Va = V_lds[oA];
        float f[2][4];
        mlp_pair(0, q, nh, Sa, Va, tA, w0t4, w1p, b1v, w2v, b2s, f);

        {   // S update, writer lanes nh<4 handle rows 4q+nh
            const int r = nh & 3;
            const float f0 = select4(f[0][0], f[0][1], f[0][2], f[0][3], r);
            const float f1 = select4(f[1][0], f[1][1], f[1][2], f[1][3], r);
            const float Sn = S_lds[oW] * fmaf(f1, z1, fmaf(f0, dtw, 1.0f));
            if (nh < 4) S_lds[oW] = Sn;
        }

        // ---- phase 2: nets 2,3 on (S_new, V, rf, t) ----
        Sa = S_lds[oA];                             // updated S, same wave
        float g[2][4];
        mlp_pair(2, q, nh, Sa, Va, tA, w0t4, w1p, b1v, w2v, b2s, g);

        {
            const int r = nh & 3;
            const float g0 = select4(g[0][0], g[0][1], g[0][2], g[0][3], r);
            const float g1 = select4(g[1][0], g[1][1], g[1][2], g[1][3], r);
            const float Vn = V_lds[oW] * fmaf(g1, sqw * z2, fmaf(g0, dtw, 1.0f));
            if (nh < 4) V_lds[oW] = Vn;
        }
    }

    // ---- payoff: block partial per option (2 paths) ----
    __syncthreads();
    if (tid < 128) {
        const int opt = tid & 63;
        const int p   = blockIdx.x * 2 + (tid >> 6);
        const float Tt   = Tp[opt];
        const float disc = __builtin_amdgcn_exp2f(-rf * Tt * 1.4426950408889634f)
                           * (1.0f / (float)N_PATHS);
        const float Kv = Kp[opt];
        const float s1 = S_lds[tid];
        const float p1 = (s1 - Kv < 0.0f) ? 0.0f : s1;
        const float v  = disc * p1;
        if (use_ws) ws[p * 64 + opt] = v;
        else        atomicAdd(&out[opt], v);
    }
}

__global__ void reduce_kernel(const float* __restrict__ ws, float* __restrict__ out) {
    __shared__ float acc[4][64];
    const int o = threadIdx.x & 63, g = threadIdx.x >> 6;
    float s = 0.0f;
    for (int b = g; b < N_PATHS; b += 4) s += ws[b * 64 + o];
    acc[g][o] = s;
    __syncthreads();
    if (threadIdx.x < 64)
        out[threadIdx.x] = acc[0][threadIdx.x] + acc[1][threadIdx.x]
                         + acc[2][threadIdx.x] + acc[3][threadIdx.x];
}

__global__ void zero_out_kernel(float* __restrict__ out) {
    out[threadIdx.x] = 0.0f;
}

extern "C" void kernel_launch(void* const* d_in, const int* in_sizes, int n_in,
                              void* d_out, int out_size, void* d_ws, size_t ws_size,
                              hipStream_t stream) {
    const float* S0p = (const float*)d_in[0];
    const float* Kp  = (const float*)d_in[1];
    const float* Tp  = (const float*)d_in[2];
    const float* rfp = (const float*)d_in[3];
    const float* Z1  = (const float*)d_in[4];
    const float* Z2  = (const float*)d_in[5];
    const float* W0  = (const float*)d_in[6];
    const float* b0  = (const float*)d_in[7];
    const float* W1  = (const float*)d_in[8];
    const float* b1  = (const float*)d_in[9];
    const float* W2  = (const float*)d_in[10];
    const float* b2  = (const float*)d_in[11];
    float* out = (float*)d_out;
    float* wsf = (float*)d_ws;

    const int use_ws = (ws_size >= (size_t)(N_PATHS * 64 * sizeof(float))) ? 1 : 0;

    if (!use_ws) zero_out_kernel<<<1, B_OPTS, 0, stream>>>(out);
    nsde_kernel<<<N_PATHS / 2, 512, 0, stream>>>(S0p, Kp, Tp, rfp, Z1, Z2,
                                                 W0, b0, W1, b1, W2, b2, out, wsf, use_ws);
    if (use_ws) reduce_kernel<<<1, 256, 0, stream>>>(wsf, out);
}

// Round 5
// 305.611 us; speedup vs baseline: 2.2780x; 2.2780x over previous
//
#include <hip/hip_runtime.h>

// NSDE pricer, R8: kill LICM register-caching -> real 2 waves/SIMD.
// Evidence chain: R6b (unconstrained) = VGPR 236, no spill, 1 wave/SIMD ->
// arch+AGPR total >256 blocks co-residency. R5/R7 (occupancy forced) = arch
// VGPR capped at 128 (VGPR/AGPR split of the 256 budget) and LICM-hoisted
// step-invariant LDS reads (32 W1 frags = 128 regs + w0t4) spill to scratch
// -> 1.7 GB HBM reload. Fix: asm memory barrier per phase inside the step
// loop forbids cross-iteration caching of LDS values (re-read from LDS each
// phase, cheap DS-pipe ops) -> live set ~100-130 regs -> amdgpu_waves_per_eu(2)
// gives 2 waves/SIMD with NO spill. Geometry identical to R6b: 256-thr block
// = 4 waves = 1 path, grid 512, W1 bf16 B-frags in LDS (lane-contiguous
// ds_read_b128), layer2 = 8x mfma_f32_16x16x32_bf16 per net, layer1/3 + tanh
// fp32 VALU, S/V in per-wave LDS slices, no __syncthreads in step loop.

#define N_PATHS 512
#define N_STEPS 32
#define B_OPTS  64
#define HID     64

typedef __attribute__((ext_vector_type(8))) short bf16x8;   // 8 bf16 (4 VGPRs)
typedef __attribute__((ext_vector_type(4))) float f32x4;

__device__ __forceinline__ float fast_tanh(float x) {
    // tanh(x) = 1 - 2/(e^{2x}+1); exp2-based, correct saturation at +/-inf.
    float u = __builtin_amdgcn_exp2f(x * 2.8853900817779268f);
    float r = __builtin_amdgcn_rcpf(u + 1.0f);
    return fmaf(-2.0f, r, 1.0f);
}

__device__ __forceinline__ short f2bf(float f) {            // fp32 -> bf16 RNE
    union { float f; unsigned u; } c; c.f = f;
    unsigned u = c.u + 0x7FFFu + ((c.u >> 16) & 1u);
    return (short)(u >> 16);
}

__device__ __forceinline__ float select4(float a0, float a1, float a2, float a3, int idx) {
    float lo = (idx & 1) ? a1 : a0;
    float hi = (idx & 1) ? a3 : a2;
    return (idx & 2) ? hi : lo;
}

// Two nets of one phase: layer1 (VALU, A-layout), layer2 (MFMA, W1 frags from
// LDS), layer3+tanh. fout[nn][reg] = f for row (4q + reg) of this wave's
// 16-row tile, all lanes valid after the shfl reduce.
__device__ __forceinline__ void mlp_pair(
    int base, int q, int nh,
    float Sa, float Va, float tA,
    const float4* __restrict__ w0t4,            // LDS, [4][72] swizzled
    const uint4* __restrict__ w1p,              // LDS frags, pre-offset by lane
    const float (&b1v)[4][4], const float (&w2v)[4][4], const float (&b2s)[4],
    float (&fout)[2][4])
{
    // Block LICM: nothing memory-derived may be carried across phases/steps.
    // LDS re-reads are cheap (DS pipe); scratch spills of hoisted values are
    // not (R5/R7: 1.7 GB HBM reload).
    asm volatile("" ::: "memory");
#pragma unroll
    for (int nn = 0; nn < 2; ++nn) {
        const int net = base + nn;
        // ---- layer1 in A-fragment layout: lane holds h1[row=nh][k=32kh+8q+j]
        bf16x8 afr[2];                           // [kh]
#pragma unroll
        for (int kh = 0; kh < 2; ++kh) {
#pragma unroll
            for (int j = 0; j < 8; ++j) {
                const int kk = kh * 32 + q * 8 + j;
                const float4 w = w0t4[net * 72 + kk + (kk >> 3)]; // bank-swizzled
                float a = fmaf(Sa, w.x, fmaf(Va, w.y, fmaf(tA, w.z, w.w)));
                afr[kh][j] = f2bf(fast_tanh(a));
            }
        }
        // ---- layer2: 1 M-tile x 4 N-tiles x 2 K-halves, W1 frags via
        // ds_read_b128 (lane-contiguous, conflict-free, immediate offsets)
        f32x4 C[4];
#pragma unroll
        for (int nt = 0; nt < 4; ++nt) {
            const bf16x8 bf0 = __builtin_bit_cast(bf16x8, w1p[((net * 4 + nt) * 2 + 0) * 64]);
            const bf16x8 bf1 = __builtin_bit_cast(bf16x8, w1p[((net * 4 + nt) * 2 + 1) * 64]);
            f32x4 c = {0.0f, 0.0f, 0.0f, 0.0f};
            c = __builtin_amdgcn_mfma_f32_16x16x32_bf16(afr[0], bf0, c, 0, 0, 0);
            c = __builtin_amdgcn_mfma_f32_16x16x32_bf16(afr[1], bf1, c, 0, 0, 0);
            C[nt] = c;
        }
        // ---- layer3: tanh, dot with W2 over nt, reduce over 16 C-columns
#pragma unroll
        for (int reg = 0; reg < 4; ++reg) {
            float s = 0.0f;
#pragma unroll
            for (int nt = 0; nt < 4; ++nt)
                s = fmaf(fast_tanh(C[nt][reg] + b1v[net][nt]), w2v[net][nt], s);
            s += __shfl_xor(s, 1);
            s += __shfl_xor(s, 2);
            s += __shfl_xor(s, 4);
            s += __shfl_xor(s, 8);
            fout[nn][reg] = s + b2s[net];
        }
    }
}

__global__ __launch_bounds__(256)
__attribute__((amdgpu_waves_per_eu(2)))
void nsde_kernel(
    const float* __restrict__ S0p, const float* __restrict__ Kp,
    const float* __restrict__ Tp,  const float* __restrict__ rfp,
    const float* __restrict__ Z1,  const float* __restrict__ Z2,
    const float* __restrict__ W0,  const float* __restrict__ b0,
    const float* __restrict__ W1,  const float* __restrict__ b1,
    const float* __restrict__ W2,  const float* __restrict__ b2,
    float* __restrict__ out, float* __restrict__ ws, int use_ws)
{
    const int tid  = threadIdx.x;
    const int wave = tid >> 6;
    const int lane = tid & 63;
    const int q    = lane >> 4;
    const int nh   = lane & 15;
    const int path = blockIdx.x;                    // one path per block

    __shared__ float  S_lds[64], V_lds[64];
    __shared__ float4 w0t4[4 * 72];                 // swizzled (w_S,w_V,w_t, b0+rf*w_rf)
    __shared__ uint4  w1f[2048];                    // W1 bf16 frags, 32 KB
                                                    // [net][nt][kh] x [q][nh]

    const float rf = rfp[0];

    // ---- one-time staging: W0 columns ----
    {
        const int net = tid >> 6, kk = tid & 63;
        const float wsv = W0[net * 256 + 0 * 64 + kk];
        const float wvv = W0[net * 256 + 1 * 64 + kk];
        const float wrv = W0[net * 256 + 2 * 64 + kk];
        const float wtv = W0[net * 256 + 3 * 64 + kk];
        w0t4[net * 72 + kk + (kk >> 3)] =
            make_float4(wsv, wvv, wtv, fmaf(rf, wrv, b0[net * 64 + kk]));
    }
    if (tid < 64) { S_lds[tid] = S0p[tid]; V_lds[tid] = 0.2f; }

    // ---- one-time staging: W1 -> LDS bf16 B-fragments ----
    // frag f: nh=f&15, q=(f>>4)&3, kh=(f>>6)&1, nt=(f>>7)&3, net=(f>>9)&3
    // holds B[k=32kh+8q+j][n=16nt+nh], j=0..7 packed (16 B).
#pragma unroll
    for (int it = 0; it < 8; ++it) {
        const int f   = it * 256 + tid;
        const int fnh = f & 15;
        const int fq  = (f >> 4) & 3;
        const int fkh = (f >> 6) & 1;
        const int fnt = (f >> 7) & 3;
        const int fnet= (f >> 9) & 3;
        const float* wp = W1 + fnet * 4096 + (fkh * 32 + fq * 8) * 64 + fnt * 16 + fnh;
        bf16x8 fr;
#pragma unroll
        for (int j = 0; j < 8; ++j) fr[j] = f2bf(wp[j * 64]);
        w1f[f] = __builtin_bit_cast(uint4, fr);
    }

    // ---- per-lane constants ----
    const int oA = wave * 16 + nh;                  // A-layout row (opt index)
    const int oW = wave * 16 + 4 * q + (nh & 3);    // writer row
    const float dta = Tp[oA] * (1.0f / N_STEPS);
    const float dtw = Tp[oW] * (1.0f / N_STEPS);
    const float sqw = sqrtf(dtw);

    float b1v[4][4], w2v[4][4], b2s[4];
#pragma unroll
    for (int net = 0; net < 4; ++net) {
        b2s[net] = b2[net];
#pragma unroll
        for (int nt = 0; nt < 4; ++nt) {
            b1v[net][nt] = b1[net * 64 + nt * 16 + nh];
            w2v[net][nt] = W2[net * 64 + nt * 16 + nh];
        }
    }

    __syncthreads();

    const uint4* __restrict__ w1p = &w1f[q * 16 + nh];  // lane-contiguous base
    const float* __restrict__ z1p = Z1 + path * N_STEPS;
    const float* __restrict__ z2p = Z2 + path * N_STEPS;

    for (int step = 0; step < N_STEPS; ++step) {
        const float z1 = z1p[step];
        const float z2 = z2p[step];
        const float tA = dta * (float)step;

        // ---- phase 1: nets 0,1 on (S, V, rf, t) ----
        float Sa = S_lds[oA];
        const float Va = V_lds[oA];
        float f[2][4];
        mlp_pair(0, q, nh, Sa, Va, tA, w0t4, w1p, b1v, w2v, b2s, f);

        {   // S update, writer lanes nh<4 handle rows 4q+nh
            const int r = nh & 3;
            const float f0 = select4(f[0][0], f[0][1], f[0][2], f[0][3], r);
            const float f1 = select4(f[1][0], f[1][1], f[1][2], f[1][3], r);
            const float Sn = S_lds[oW] * fmaf(f1, z1, fmaf(f0, dtw, 1.0f));
            if (nh < 4) S_lds[oW] = Sn;
        }

        // ---- phase 2: nets 2,3 on (S_new, V, rf, t) ----
        Sa = S_lds[oA];                             // updated S, same wave
        float g[2][4];
        mlp_pair(2, q, nh, Sa, Va, tA, w0t4, w1p, b1v, w2v, b2s, g);

        {
            const int r = nh & 3;
            const float g0 = select4(g[0][0], g[0][1], g[0][2], g[0][3], r);
            const float g1 = select4(g[1][0], g[1][1], g[1][2], g[1][3], r);
            const float Vn = V_lds[oW] * fmaf(g1, sqw * z2, fmaf(g0, dtw, 1.0f));
            if (nh < 4) V_lds[oW] = Vn;
        }
    }

    // ---- payoff: block partial per option ----
    __syncthreads();
    if (tid < 64) {
        const float Tt   = Tp[tid];
        const float disc = __builtin_amdgcn_exp2f(-rf * Tt * 1.4426950408889634f)
                           * (1.0f / (float)N_PATHS);
        const float Kv = Kp[tid];
        const float s1 = S_lds[tid];
        const float p1 = (s1 - Kv < 0.0f) ? 0.0f : s1;
        const float v  = disc * p1;
        if (use_ws) ws[path * 64 + tid] = v;
        else        atomicAdd(&out[tid], v);
    }
}

__global__ void reduce_kernel(const float* __restrict__ ws, float* __restrict__ out) {
    __shared__ float acc[4][64];
    const int o = threadIdx.x & 63, g = threadIdx.x >> 6;
    float s = 0.0f;
    for (int b = g; b < N_PATHS; b += 4) s += ws[b * 64 + o];
    acc[g][o] = s;
    __syncthreads();
    if (threadIdx.x < 64)
        out[threadIdx.x] = acc[0][threadIdx.x] + acc[1][threadIdx.x]
                         + acc[2][threadIdx.x] + acc[3][threadIdx.x];
}

__global__ void zero_out_kernel(float* __restrict__ out) {
    out[threadIdx.x] = 0.0f;
}

extern "C" void kernel_launch(void* const* d_in, const int* in_sizes, int n_in,
                              void* d_out, int out_size, void* d_ws, size_t ws_size,
                              hipStream_t stream) {
    const float* S0p = (const float*)d_in[0];
    const float* Kp  = (const float*)d_in[1];
    const float* Tp  = (const float*)d_in[2];
    const float* rfp = (const float*)d_in[3];
    const float* Z1  = (const float*)d_in[4];
    const float* Z2  = (const float*)d_in[5];
    const float* W0  = (const float*)d_in[6];
    const float* b0  = (const float*)d_in[7];
    const float* W1  = (const float*)d_in[8];
    const float* b1  = (const float*)d_in[9];
    const float* W2  = (const float*)d_in[10];
    const float* b2  = (const float*)d_in[11];
    float* out = (float*)d_out;
    float* wsf = (float*)d_ws;

    const int use_ws = (ws_size >= (size_t)(N_PATHS * 64 * sizeof(float))) ? 1 : 0;

    if (!use_ws) zero_out_kernel<<<1, B_OPTS, 0, stream>>>(out);
    nsde_kernel<<<N_PATHS, 256, 0, stream>>>(S0p, Kp, Tp, rfp, Z1, Z2,
                                             W0, b0, W1, b1, W2, b2, out, wsf, use_ws);
    if (use_ws) reduce_kernel<<<1, 256, 0, stream>>>(wsf, out);
}

// Round 6
// 284.419 us; speedup vs baseline: 2.4477x; 1.0745x over previous
//
#include <hip/hip_runtime.h>

// NSDE pricer, R9: net-split waves (2 waves per 16-row tile) + register S/V.
// R8 post-mortem: VGPR 52, no spill, 224 us, VALUBusy 75%, occupancy 20.3% =
// grid cap (2048 waves = 2/SIMD; 32768 rows / 16 per wave). Finer decomposition:
// the two nets of each phase are independent -> wave pair (role 0: nets 0/2,
// role 1: nets 1/3) co-computes one tile; per-row outputs exchanged via 64-float
// LDS + 2 __syncthreads/step. 4096 waves = 4/SIMD (2 blocks/CU x 8 waves).
// S,V now register-carried per lane (row fixed = t*16+nh); both waves compute
// the update redundantly from published fx -> no S/V LDS round-trip, no
// writer-lane divergence, no barrier before phase 2.
// Block 512 thr = 8 waves = 1 path, grid 512. W1 bf16 B-frags in LDS
// (lane-contiguous ds_read_b128), layer2 = 8x mfma_f32_16x16x32_bf16 per net,
// layer1/3 + tanh fp32 VALU. Anti-LICM asm barrier per phase (R8's key fix)
// keeps live set small -> no spill at waves_per_eu(4).

#define N_PATHS 512
#define N_STEPS 32
#define B_OPTS  64
#define HID     64

typedef __attribute__((ext_vector_type(8))) short bf16x8;   // 8 bf16 (4 VGPRs)
typedef __attribute__((ext_vector_type(4))) float f32x4;

__device__ __forceinline__ float fast_tanh(float x) {
    // tanh(x) = 1 - 2/(e^{2x}+1); exp2-based, correct saturation at +/-inf.
    float u = __builtin_amdgcn_exp2f(x * 2.8853900817779268f);
    float r = __builtin_amdgcn_rcpf(u + 1.0f);
    return fmaf(-2.0f, r, 1.0f);
}

__device__ __forceinline__ short f2bf(float f) {            // fp32 -> bf16 RNE
    union { float f; unsigned u; } c; c.f = f;
    unsigned u = c.u + 0x7FFFu + ((c.u >> 16) & 1u);
    return (short)(u >> 16);
}

__device__ __forceinline__ float select4(float a0, float a1, float a2, float a3, int idx) {
    float lo = (idx & 1) ? a1 : a0;
    float hi = (idx & 1) ? a3 : a2;
    return (idx & 2) ? hi : lo;
}

// One net: layer1 (VALU, A-layout), layer2 (MFMA, W1 frags from LDS),
// layer3+tanh+butterfly. fout[reg] = f for row (4q + reg) of this wave's
// 16-row tile, valid at all lanes after the xor-reduce.
__device__ __forceinline__ void mlp_one(
    int net, int q, int nh,
    float Sa, float Va, float tA,
    const float4* __restrict__ w0t4,            // LDS, [4][72] swizzled
    const uint4* __restrict__ w1p,              // LDS frags, pre-offset by lane
    const float (&b1v)[4], const float (&w2v)[4], float b2s,
    float (&fout)[4])
{
    // Block LICM: nothing memory-derived carried across phases/steps
    // (R5/R7 lesson: hoisted LDS values spill to scratch -> 1.7 GB HBM).
    asm volatile("" ::: "memory");
    // ---- layer1 in A-fragment layout: lane holds h1[row=nh][k=32kh+8q+j]
    bf16x8 afr[2];                               // [kh]
#pragma unroll
    for (int kh = 0; kh < 2; ++kh) {
#pragma unroll
        for (int j = 0; j < 8; ++j) {
            const int kk = kh * 32 + q * 8 + j;
            const float4 w = w0t4[net * 72 + kk + (kk >> 3)]; // bank-swizzled
            float a = fmaf(Sa, w.x, fmaf(Va, w.y, fmaf(tA, w.z, w.w)));
            afr[kh][j] = f2bf(fast_tanh(a));
        }
    }
    // ---- layer2: 1 M-tile x 4 N-tiles x 2 K-halves
    f32x4 C[4];
#pragma unroll
    for (int nt = 0; nt < 4; ++nt) {
        const bf16x8 bf0 = __builtin_bit_cast(bf16x8, w1p[((net * 4 + nt) * 2 + 0) * 64]);
        const bf16x8 bf1 = __builtin_bit_cast(bf16x8, w1p[((net * 4 + nt) * 2 + 1) * 64]);
        f32x4 c = {0.0f, 0.0f, 0.0f, 0.0f};
        c = __builtin_amdgcn_mfma_f32_16x16x32_bf16(afr[0], bf0, c, 0, 0, 0);
        c = __builtin_amdgcn_mfma_f32_16x16x32_bf16(afr[1], bf1, c, 0, 0, 0);
        C[nt] = c;
    }
    // ---- layer3: tanh, dot with W2 over nt, butterfly over 16 C-columns
#pragma unroll
    for (int reg = 0; reg < 4; ++reg) {
        float s = 0.0f;
#pragma unroll
        for (int nt = 0; nt < 4; ++nt)
            s = fmaf(fast_tanh(C[nt][reg] + b1v[nt]), w2v[nt], s);
        s += __shfl_xor(s, 1);
        s += __shfl_xor(s, 2);
        s += __shfl_xor(s, 4);
        s += __shfl_xor(s, 8);
        fout[reg] = s + b2s;
    }
}

__global__ __launch_bounds__(512)
__attribute__((amdgpu_waves_per_eu(4)))
void nsde_kernel(
    const float* __restrict__ S0p, const float* __restrict__ Kp,
    const float* __restrict__ Tp,  const float* __restrict__ rfp,
    const float* __restrict__ Z1,  const float* __restrict__ Z2,
    const float* __restrict__ W0,  const float* __restrict__ b0,
    const float* __restrict__ W1,  const float* __restrict__ b1,
    const float* __restrict__ W2,  const float* __restrict__ b2,
    float* __restrict__ out, float* __restrict__ ws, int use_ws)
{
    const int tid  = threadIdx.x;
    const int wave = tid >> 6;                      // 0..7
    const int lane = tid & 63;
    const int q    = lane >> 4;
    const int nh   = lane & 15;
    const int t    = wave >> 1;                     // tile 0..3
    const int role = wave & 1;                      // 0: nets 0/2, 1: nets 1/3
    const int path = blockIdx.x;                    // one path per block
    const int row  = t * 16 + nh;                   // this lane's option row

    __shared__ float4 w0t4[4 * 72];                 // swizzled (w_S,w_V,w_t, b0+rf*w_rf)
    __shared__ uint4  w1f[2048];                    // W1 bf16 frags, 32 KB
    __shared__ float  fx[2][64];                    // phase-1 exchange [role][row]
    __shared__ float  gx[2][64];                    // phase-2 exchange

    const float rf = rfp[0];

    // ---- one-time staging: W0 columns ----
    if (tid < 256) {
        const int net = tid >> 6, kk = tid & 63;
        const float wsv = W0[net * 256 + 0 * 64 + kk];
        const float wvv = W0[net * 256 + 1 * 64 + kk];
        const float wrv = W0[net * 256 + 2 * 64 + kk];
        const float wtv = W0[net * 256 + 3 * 64 + kk];
        w0t4[net * 72 + kk + (kk >> 3)] =
            make_float4(wsv, wvv, wtv, fmaf(rf, wrv, b0[net * 64 + kk]));
    }

    // ---- one-time staging: W1 -> LDS bf16 B-fragments ----
    // frag f: nh=f&15, q=(f>>4)&3, kh=(f>>6)&1, nt=(f>>7)&3, net=(f>>9)&3
#pragma unroll
    for (int it = 0; it < 4; ++it) {
        const int f   = it * 512 + tid;
        const int fnh = f & 15;
        const int fq  = (f >> 4) & 3;
        const int fkh = (f >> 6) & 1;
        const int fnt = (f >> 7) & 3;
        const int fnet= (f >> 9) & 3;
        const float* wp = W1 + fnet * 4096 + (fkh * 32 + fq * 8) * 64 + fnt * 16 + fnh;
        bf16x8 fr;
#pragma unroll
        for (int j = 0; j < 8; ++j) fr[j] = f2bf(wp[j * 64]);
        w1f[f] = __builtin_bit_cast(uint4, fr);
    }

    // ---- per-lane constants (only this wave's two nets) ----
    const float dta  = Tp[row] * (1.0f / N_STEPS);
    const float sqdt = sqrtf(dta);
    const int netA = role;                          // phase-1 net
    const int netB = role + 2;                      // phase-2 net

    float b1vA[4], w2vA[4], b1vB[4], w2vB[4];
#pragma unroll
    for (int nt = 0; nt < 4; ++nt) {
        b1vA[nt] = b1[netA * 64 + nt * 16 + nh];
        w2vA[nt] = W2[netA * 64 + nt * 16 + nh];
        b1vB[nt] = b1[netB * 64 + nt * 16 + nh];
        w2vB[nt] = W2[netB * 64 + nt * 16 + nh];
    }
    const float b2A = b2[netA], b2B = b2[netB];

    float Sreg = S0p[row];                          // register-carried state
    float Vreg = 0.2f;

    __syncthreads();

    const uint4* __restrict__ w1p = &w1f[q * 16 + nh];  // lane-contiguous base
    const float* __restrict__ z1p = Z1 + path * N_STEPS;
    const float* __restrict__ z2p = Z2 + path * N_STEPS;

    for (int step = 0; step < N_STEPS; ++step) {
        const float z1 = z1p[step];
        const float z2 = z2p[step];
        const float tA = dta * (float)step;

        // ---- phase 1: my net (role) on (S, V, rf, t) ----
        float f[4];
        mlp_one(netA, q, nh, Sreg, Vreg, tA, w0t4, w1p, b1vA, w2vA, b2A, f);
        if (nh < 4) fx[role][t * 16 + 4 * q + nh] = select4(f[0], f[1], f[2], f[3], nh);
        __syncthreads();
        {   // both waves update S redundantly (deterministic, same inputs)
            const float f0r = fx[0][row];
            const float f1r = fx[1][row];
            Sreg = Sreg * fmaf(f1r, z1, fmaf(f0r, dta, 1.0f));
        }

        // ---- phase 2: my net (role+2) on (S_new, V, rf, t) ----
        float g[4];
        mlp_one(netB, q, nh, Sreg, Vreg, tA, w0t4, w1p, b1vB, w2vB, b2B, g);
        if (nh < 4) gx[role][t * 16 + 4 * q + nh] = select4(g[0], g[1], g[2], g[3], nh);
        __syncthreads();
        {
            const float g2r = gx[0][row];
            const float g3r = gx[1][row];
            Vreg = Vreg * fmaf(g3r, sqdt * z2, fmaf(g2r, dta, 1.0f));
        }
    }

    // ---- payoff: one lane per row writes (no extra barrier needed) ----
    if (role == 0 && q == 0) {
        const float Tt   = dta * (float)N_STEPS;
        const float disc = __builtin_amdgcn_exp2f(-rf * Tt * 1.4426950408889634f)
                           * (1.0f / (float)N_PATHS);
        const float Kv = Kp[row];
        const float p1 = (Sreg - Kv < 0.0f) ? 0.0f : Sreg;
        const float v  = disc * p1;
        if (use_ws) ws[path * 64 + row] = v;
        else        atomicAdd(&out[row], v);
    }
}

__global__ void reduce_kernel(const float* __restrict__ ws, float* __restrict__ out) {
    __shared__ float acc[4][64];
    const int o = threadIdx.x & 63, g = threadIdx.x >> 6;
    float s = 0.0f;
    for (int b = g; b < N_PATHS; b += 4) s += ws[b * 64 + o];
    acc[g][o] = s;
    __syncthreads();
    if (threadIdx.x < 64)
        out[threadIdx.x] = acc[0][threadIdx.x] + acc[1][threadIdx.x]
                         + acc[2][threadIdx.x] + acc[3][threadIdx.x];
}

__global__ void zero_out_kernel(float* __restrict__ out) {
    out[threadIdx.x] = 0.0f;
}

extern "C" void kernel_launch(void* const* d_in, const int* in_sizes, int n_in,
                              void* d_out, int out_size, void* d_ws, size_t ws_size,
                              hipStream_t stream) {
    const float* S0p = (const float*)d_in[0];
    const float* Kp  = (const float*)d_in[1];
    const float* Tp  = (const float*)d_in[2];
    const float* rfp = (const float*)d_in[3];
    const float* Z1  = (const float*)d_in[4];
    const float* Z2  = (const float*)d_in[5];
    const float* W0  = (const float*)d_in[6];
    const float* b0  = (const float*)d_in[7];
    const float* W1  = (const float*)d_in[8];
    const float* b1  = (const float*)d_in[9];
    const float* W2  = (const float*)d_in[10];
    const float* b2  = (const float*)d_in[11];
    float* out = (float*)d_out;
    float* wsf = (float*)d_ws;

    const int use_ws = (ws_size >= (size_t)(N_PATHS * 64 * sizeof(float))) ? 1 : 0;

    if (!use_ws) zero_out_kernel<<<1, B_OPTS, 0, stream>>>(out);
    nsde_kernel<<<N_PATHS, 512, 0, stream>>>(S0p, Kp, Tp, rfp, Z1, Z2,
                                             W0, b0, W1, b1, W2, b2, out, wsf, use_ws);
    if (use_ws) reduce_kernel<<<1, 256, 0, stream>>>(wsf, out);
}

// Round 8
// 263.663 us; speedup vs baseline: 2.6404x; 1.0787x over previous
//
#include <hip/hip_runtime.h>

// NSDE pricer, R10b: resubmit of R10 (bench infra failed twice; no counters).
// VALU op-count reduction on the R9 structure.
// R9 post-mortem: 205 us, VALUBusy 85%, occupancy 37.4% (= 4 waves/SIMD cap
// set by 32KB w1f LDS x one-path-per-block recurrence), VGPR 40, no spill.
// Issue-bound -> remove ops, keep structure:
//  1. tanh pre-scale k=2/ln2 folded into staged weights (w0t4, W1, b1):
//     fma/MFMA chains directly produce the exp2 argument (-32 mul/mlp_one).
//  2. b1 folded into MFMA C-init (C col = nh for all 4 regs -> splat is legal)
//     (-16 add/mlp_one).
//  3. h1->bf16 via v_cvt_pk_bf16_f32 (2 floats -> packed dword, 1 op) instead
//     of hand-rolled RNE + short packing (~80 -> 8 ops/mlp_one).
// Geometry unchanged: block 512 = 8 waves = 1 path (2 waves/tile net-split:
// role 0 nets 0/2, role 1 nets 1/3), grid 512, S/V register-carried,
// exchange via 64-float LDS + 2 barriers/step, W1 bf16 B-frags in LDS
// (lane-contiguous ds_read_b128), anti-LICM asm barrier per phase (R8 fix).

#define N_PATHS 512
#define N_STEPS 32
#define B_OPTS  64
#define HID     64

#define TANH_K 2.8853900817779268f   // 2/ln2: tanh(x) = 1 - 2/(2^(k*x)+1)

typedef __attribute__((ext_vector_type(8))) short bf16x8;   // 8 bf16 (4 VGPRs)
typedef __attribute__((ext_vector_type(4))) float f32x4;
typedef __attribute__((ext_vector_type(4))) unsigned u32x4;

__device__ __forceinline__ float tanh_from_scaled(float a) {
    // a = k*x already (k folded into weights). tanh = 1 - 2/(2^a + 1).
    float u = __builtin_amdgcn_exp2f(a);
    float r = __builtin_amdgcn_rcpf(u + 1.0f);
    return fmaf(-2.0f, r, 1.0f);
}

__device__ __forceinline__ short f2bf(float f) {            // fp32 -> bf16 RNE
    union { float f; unsigned u; } c; c.f = f;
    unsigned u = c.u + 0x7FFFu + ((c.u >> 16) & 1u);
    return (short)(u >> 16);
}

__device__ __forceinline__ unsigned cvt_pk_bf16(float lo, float hi) {
    // packs lo -> [15:0], hi -> [31:16] as bf16 (RNE), single VALU op.
    unsigned r;
    asm("v_cvt_pk_bf16_f32 %0, %1, %2" : "=v"(r) : "v"(lo), "v"(hi));
    return r;
}

__device__ __forceinline__ float select4(float a0, float a1, float a2, float a3, int idx) {
    float lo = (idx & 1) ? a1 : a0;
    float hi = (idx & 1) ? a3 : a2;
    return (idx & 2) ? hi : lo;
}

// One net: layer1 (VALU, A-layout), layer2 (MFMA, W1 frags from LDS, b1 in
// C-init), layer3+tanh+butterfly. fout[reg] = f for row (4q + reg) of this
// wave's 16-row tile, valid at all lanes after the xor-reduce.
__device__ __forceinline__ void mlp_one(
    int net, int q, int nh,
    float Sa, float Va, float tA,
    const float4* __restrict__ w0t4,            // LDS, [4][72] swizzled, k-scaled
    const uint4* __restrict__ w1p,              // LDS frags (k-scaled), lane-offset
    const float (&b1v)[4], const float (&w2v)[4], float b2s,
    float (&fout)[4])
{
    // Block LICM: nothing memory-derived carried across phases/steps
    // (R5/R7 lesson: hoisted LDS values spill to scratch -> 1.7 GB HBM).
    asm volatile("" ::: "memory");
    // ---- layer1 in A-fragment layout: lane holds h1[row=nh][k=32kh+8q+j]
    u32x4 afr[2];                                // [kh], 8 bf16 each
#pragma unroll
    for (int kh = 0; kh < 2; ++kh) {
        float tv[8];
#pragma unroll
        for (int j = 0; j < 8; ++j) {
            const int kk = kh * 32 + q * 8 + j;
            const float4 w = w0t4[net * 72 + kk + (kk >> 3)]; // bank-swizzled
            const float a = fmaf(Sa, w.x, fmaf(Va, w.y, fmaf(tA, w.z, w.w)));
            tv[j] = tanh_from_scaled(a);         // w pre-scaled by k
        }
#pragma unroll
        for (int d = 0; d < 4; ++d)
            afr[kh][d] = cvt_pk_bf16(tv[2 * d], tv[2 * d + 1]);
    }
    const bf16x8 a0 = __builtin_bit_cast(bf16x8, afr[0]);
    const bf16x8 a1 = __builtin_bit_cast(bf16x8, afr[1]);
    // ---- layer2: 1 M-tile x 4 N-tiles x 2 K-halves; C-init = k*b1 (col=nh)
    f32x4 C[4];
#pragma unroll
    for (int nt = 0; nt < 4; ++nt) {
        const bf16x8 bf0 = __builtin_bit_cast(bf16x8, w1p[((net * 4 + nt) * 2 + 0) * 64]);
        const bf16x8 bf1 = __builtin_bit_cast(bf16x8, w1p[((net * 4 + nt) * 2 + 1) * 64]);
        f32x4 c = {b1v[nt], b1v[nt], b1v[nt], b1v[nt]};
        c = __builtin_amdgcn_mfma_f32_16x16x32_bf16(a0, bf0, c, 0, 0, 0);
        c = __builtin_amdgcn_mfma_f32_16x16x32_bf16(a1, bf1, c, 0, 0, 0);
        C[nt] = c;
    }
    // ---- layer3: tanh (arg already scaled), dot W2 over nt, butterfly reduce
#pragma unroll
    for (int reg = 0; reg < 4; ++reg) {
        float s = 0.0f;
#pragma unroll
        for (int nt = 0; nt < 4; ++nt)
            s = fmaf(tanh_from_scaled(C[nt][reg]), w2v[nt], s);
        s += __shfl_xor(s, 1);
        s += __shfl_xor(s, 2);
        s += __shfl_xor(s, 4);
        s += __shfl_xor(s, 8);
        fout[reg] = s + b2s;
    }
}

__global__ __launch_bounds__(512)
__attribute__((amdgpu_waves_per_eu(4)))
void nsde_kernel(
    const float* __restrict__ S0p, const float* __restrict__ Kp,
    const float* __restrict__ Tp,  const float* __restrict__ rfp,
    const float* __restrict__ Z1,  const float* __restrict__ Z2,
    const float* __restrict__ W0,  const float* __restrict__ b0,
    const float* __restrict__ W1,  const float* __restrict__ b1,
    const float* __restrict__ W2,  const float* __restrict__ b2,
    float* __restrict__ out, float* __restrict__ ws, int use_ws)
{
    const int tid  = threadIdx.x;
    const int wave = tid >> 6;                      // 0..7
    const int lane = tid & 63;
    const int q    = lane >> 4;
    const int nh   = lane & 15;
    const int t    = wave >> 1;                     // tile 0..3
    const int role = wave & 1;                      // 0: nets 0/2, 1: nets 1/3
    const int path = blockIdx.x;                    // one path per block
    const int row  = t * 16 + nh;                   // this lane's option row

    __shared__ float4 w0t4[4 * 72];                 // k*(w_S,w_V,w_t, b0+rf*w_rf)
    __shared__ uint4  w1f[2048];                    // k*W1 bf16 frags, 32 KB
    __shared__ float  fx[2][64];                    // phase-1 exchange [role][row]
    __shared__ float  gx[2][64];                    // phase-2 exchange

    const float rf = rfp[0];

    // ---- one-time staging: W0 columns (pre-scaled by TANH_K) ----
    if (tid < 256) {
        const int net = tid >> 6, kk = tid & 63;
        const float wsv = W0[net * 256 + 0 * 64 + kk];
        const float wvv = W0[net * 256 + 1 * 64 + kk];
        const float wrv = W0[net * 256 + 2 * 64 + kk];
        const float wtv = W0[net * 256 + 3 * 64 + kk];
        w0t4[net * 72 + kk + (kk >> 3)] =
            make_float4(TANH_K * wsv, TANH_K * wvv, TANH_K * wtv,
                        TANH_K * fmaf(rf, wrv, b0[net * 64 + kk]));
    }

    // ---- one-time staging: k*W1 -> LDS bf16 B-fragments ----
    // frag f: nh=f&15, q=(f>>4)&3, kh=(f>>6)&1, nt=(f>>7)&3, net=(f>>9)&3
#pragma unroll
    for (int it = 0; it < 4; ++it) {
        const int f   = it * 512 + tid;
        const int fnh = f & 15;
        const int fq  = (f >> 4) & 3;
        const int fkh = (f >> 6) & 1;
        const int fnt = (f >> 7) & 3;
        const int fnet= (f >> 9) & 3;
        const float* wp = W1 + fnet * 4096 + (fkh * 32 + fq * 8) * 64 + fnt * 16 + fnh;
        bf16x8 fr;
#pragma unroll
        for (int j = 0; j < 8; ++j) fr[j] = f2bf(TANH_K * wp[j * 64]);
        w1f[f] = __builtin_bit_cast(uint4, fr);
    }

    // ---- per-lane constants (only this wave's two nets) ----
    const float dta  = Tp[row] * (1.0f / N_STEPS);
    const float sqdt = sqrtf(dta);
    const int netA = role;                          // phase-1 net
    const int netB = role + 2;                      // phase-2 net

    float b1vA[4], w2vA[4], b1vB[4], w2vB[4];       // b1 pre-scaled by k
#pragma unroll
    for (int nt = 0; nt < 4; ++nt) {
        b1vA[nt] = TANH_K * b1[netA * 64 + nt * 16 + nh];
        w2vA[nt] = W2[netA * 64 + nt * 16 + nh];
        b1vB[nt] = TANH_K * b1[netB * 64 + nt * 16 + nh];
        w2vB[nt] = W2[netB * 64 + nt * 16 + nh];
    }
    const float b2A = b2[netA], b2B = b2[netB];

    float Sreg = S0p[row];                          // register-carried state
    float Vreg = 0.2f;

    __syncthreads();

    const uint4* __restrict__ w1p = &w1f[q * 16 + nh];  // lane-contiguous base
    const float* __restrict__ z1p = Z1 + path * N_STEPS;
    const float* __restrict__ z2p = Z2 + path * N_STEPS;

    for (int step = 0; step < N_STEPS; ++step) {
        const float z1 = z1p[step];
        const float z2 = z2p[step];
        const float tA = dta * (float)step;

        // ---- phase 1: my net (role) on (S, V, rf, t) ----
        float f[4];
        mlp_one(netA, q, nh, Sreg, Vreg, tA, w0t4, w1p, b1vA, w2vA, b2A, f);
        if (nh < 4) fx[role][t * 16 + 4 * q + nh] = select4(f[0], f[1], f[2], f[3], nh);
        __syncthreads();
        {   // both waves update S redundantly (deterministic, same inputs)
            const float f0r = fx[0][row];
            const float f1r = fx[1][row];
            Sreg = Sreg * fmaf(f1r, z1, fmaf(f0r, dta, 1.0f));
        }

        // ---- phase 2: my net (role+2) on (S_new, V, rf, t) ----
        float g[4];
        mlp_one(netB, q, nh, Sreg, Vreg, tA, w0t4, w1p, b1vB, w2vB, b2B, g);
        if (nh < 4) gx[role][t * 16 + 4 * q + nh] = select4(g[0], g[1], g[2], g[3], nh);
        __syncthreads();
        {
            const float g2r = gx[0][row];
            const float g3r = gx[1][row];
            Vreg = Vreg * fmaf(g3r, sqdt * z2, fmaf(g2r, dta, 1.0f));
        }
    }

    // ---- payoff: one lane per row writes (no extra barrier needed) ----
    if (role == 0 && q == 0) {
        const float Tt   = dta * (float)N_STEPS;
        const float disc = __builtin_amdgcn_exp2f(-rf * Tt * 1.4426950408889634f)
                           * (1.0f / (float)N_PATHS);
        const float Kv = Kp[row];
        const float p1 = (Sreg - Kv < 0.0f) ? 0.0f : Sreg;
        const float v  = disc * p1;
        if (use_ws) ws[path * 64 + row] = v;
        else        atomicAdd(&out[row], v);
    }
}

__global__ void reduce_kernel(const float* __restrict__ ws, float* __restrict__ out) {
    __shared__ float acc[4][64];
    const int o = threadIdx.x & 63, g = threadIdx.x >> 6;
    float s = 0.0f;
    for (int b = g; b < N_PATHS; b += 4) s += ws[b * 64 + o];
    acc[g][o] = s;
    __syncthreads();
    if (threadIdx.x < 64)
        out[threadIdx.x] = acc[0][threadIdx.x] + acc[1][threadIdx.x]
                         + acc[2][threadIdx.x] + acc[3][threadIdx.x];
}

__global__ void zero_out_kernel(float* __restrict__ out) {
    out[threadIdx.x] = 0.0f;
}

extern "C" void kernel_launch(void* const* d_in, const int* in_sizes, int n_in,
                              void* d_out, int out_size, void* d_ws, size_t ws_size,
                              hipStream_t stream) {
    const float* S0p = (const float*)d_in[0];
    const float* Kp  = (const float*)d_in[1];
    const float* Tp  = (const float*)d_in[2];
    const float* rfp = (const float*)d_in[3];
    const float* Z1  = (const float*)d_in[4];
    const float* Z2  = (const float*)d_in[5];
    const float* W0  = (const float*)d_in[6];
    const float* b0  = (const float*)d_in[7];
    const float* W1  = (const float*)d_in[8];
    const float* b1  = (const float*)d_in[9];
    const float* W2  = (const float*)d_in[10];
    const float* b2  = (const float*)d_in[11];
    float* out = (float*)d_out;
    float* wsf = (float*)d_ws;

    const int use_ws = (ws_size >= (size_t)(N_PATHS * 64 * sizeof(float))) ? 1 : 0;

    if (!use_ws) zero_out_kernel<<<1, B_OPTS, 0, stream>>>(out);
    nsde_kernel<<<N_PATHS, 512, 0, stream>>>(S0p, Kp, Tp, rfp, Z1, Z2,
                                             W0, b0, W1, b1, W2, b2, out, wsf, use_ws);
    if (use_ws) reduce_kernel<<<1, 256, 0, stream>>>(wsf, out);
}

// Round 9
// 246.265 us; speedup vs baseline: 2.8269x; 1.0706x over previous
//
#include <hip/hip_runtime.h>

// NSDE pricer, R11: swapped-operand MFMA -> lane-local layer3 reduce.
// R10b post-mortem: 180 us, VALUBusy 78.8%, VGPR 48, occupancy 37.6%. Layer3
// tail = 16 shfl_xor (4-deep butterfly) + select4 per phase = serial DS-pipe
// latency. Fix (T12 idea): mfma(A=W1frag, B=h1frag) instead of (h1,W1).
// Both frags already have the right lane layouts (identical (nh, 32kh+8q+j)
// mapping), so layer1 and the w1f LDS data are UNCHANGED. Output C[m=4q+r]
// [n=nh] = h2[row=nh][hidden=16nt+4q+r]: each lane holds 16 hidden of ITS OWN
// row -> layer3 = lane-local tanh-dot with per-lane W2, reduce = 2 shfl_xor
// (16,32) over q-groups, no select4, scalar output. b1 C-init comes from a
// k-scaled LDS array via aligned f32x4 broadcast read (saves 32 VGPRs vs regs).
// Geometry unchanged: block 512 = 8 waves = 1 path (net-split pairs), grid
// 512, S/V register-carried, fx/gx LDS exchange + 2 barriers/step, W1 bf16
// B-frags in LDS, anti-LICM asm barrier per phase (R8 fix), k=2/ln2 folded
// into weights (R10), b1 in MFMA C-init (R10), v_cvt_pk_bf16_f32 (R10).

#define N_PATHS 512
#define N_STEPS 32
#define B_OPTS  64
#define HID     64

#define TANH_K 2.8853900817779268f   // 2/ln2: tanh(x) = 1 - 2/(2^(k*x)+1)

typedef __attribute__((ext_vector_type(8))) short bf16x8;   // 8 bf16 (4 VGPRs)
typedef __attribute__((ext_vector_type(4))) float f32x4;
typedef __attribute__((ext_vector_type(4))) unsigned u32x4;

__device__ __forceinline__ float tanh_from_scaled(float a) {
    // a = k*x already (k folded into weights). tanh = 1 - 2/(2^a + 1).
    float u = __builtin_amdgcn_exp2f(a);
    float r = __builtin_amdgcn_rcpf(u + 1.0f);
    return fmaf(-2.0f, r, 1.0f);
}

__device__ __forceinline__ short f2bf(float f) {            // fp32 -> bf16 RNE
    union { float f; unsigned u; } c; c.f = f;
    unsigned u = c.u + 0x7FFFu + ((c.u >> 16) & 1u);
    return (short)(u >> 16);
}

__device__ __forceinline__ unsigned cvt_pk_bf16(float lo, float hi) {
    // packs lo -> [15:0], hi -> [31:16] as bf16 (RNE), single VALU op.
    unsigned r;
    asm("v_cvt_pk_bf16_f32 %0, %1, %2" : "=v"(r) : "v"(lo), "v"(hi));
    return r;
}

// One net, swapped layout: layer1 (VALU, h1 frag), layer2 MFMA(A=W1,B=h1,
// C-init=k*b1 from LDS), layer3 lane-local dot + 2-shfl reduce.
// Returns f for row nh, valid at ALL lanes.
__device__ __forceinline__ float mlp_one(
    int net, int q, int nh,
    float Sa, float Va, float tA,
    const float4* __restrict__ w0t4,            // LDS, [4][72] swizzled, k-scaled
    const uint4*  __restrict__ w1p,             // LDS frags (k-scaled), lane-offset
    const float*  __restrict__ b1k,             // LDS, k*b1, [4][64]
    const float (&w2v)[4][4], float b2s)        // [nt][r] = W2[net*64+16nt+4q+r]
{
    // Block LICM: nothing memory-derived carried across phases/steps
    // (R5/R7 lesson: hoisted LDS values spill to scratch -> 1.7 GB HBM).
    asm volatile("" ::: "memory");
    // ---- layer1: lane holds h1[row=nh][k=32kh+8q+j] as bf16 ----
    u32x4 afr[2];                                // [kh], 8 bf16 each
#pragma unroll
    for (int kh = 0; kh < 2; ++kh) {
        float tv[8];
#pragma unroll
        for (int j = 0; j < 8; ++j) {
            const int kk = kh * 32 + q * 8 + j;
            const float4 w = w0t4[net * 72 + kk + (kk >> 3)]; // bank-swizzled
            const float a = fmaf(Sa, w.x, fmaf(Va, w.y, fmaf(tA, w.z, w.w)));
            tv[j] = tanh_from_scaled(a);         // w pre-scaled by k
        }
#pragma unroll
        for (int d = 0; d < 4; ++d)
            afr[kh][d] = cvt_pk_bf16(tv[2 * d], tv[2 * d + 1]);
    }
    const bf16x8 h0 = __builtin_bit_cast(bf16x8, afr[0]);
    const bf16x8 h1 = __builtin_bit_cast(bf16x8, afr[1]);
    // ---- layer2+3: per nt, C[m=4q+r][n=nh] = h2[row=nh][hid=16nt+4q+r] ----
    float p[4];
#pragma unroll
    for (int nt = 0; nt < 4; ++nt) {
        const bf16x8 wf0 = __builtin_bit_cast(bf16x8, w1p[((net * 4 + nt) * 2 + 0) * 64]);
        const bf16x8 wf1 = __builtin_bit_cast(bf16x8, w1p[((net * 4 + nt) * 2 + 1) * 64]);
        f32x4 c = *(const f32x4*)&b1k[net * 64 + nt * 16 + 4 * q];  // b128 broadcast
        c = __builtin_amdgcn_mfma_f32_16x16x32_bf16(wf0, h0, c, 0, 0, 0);
        c = __builtin_amdgcn_mfma_f32_16x16x32_bf16(wf1, h1, c, 0, 0, 0);
        float s = 0.0f;
#pragma unroll
        for (int r = 0; r < 4; ++r)
            s = fmaf(tanh_from_scaled(c[r]), w2v[nt][r], s);
        p[nt] = s;
    }
    float s = (p[0] + p[1]) + (p[2] + p[3]);     // hidden subset of this q
    s += __shfl_xor(s, 16);                      // reduce over q (lane bits 4,5)
    s += __shfl_xor(s, 32);
    return s + b2s;
}

__global__ __launch_bounds__(512)
__attribute__((amdgpu_waves_per_eu(4)))
void nsde_kernel(
    const float* __restrict__ S0p, const float* __restrict__ Kp,
    const float* __restrict__ Tp,  const float* __restrict__ rfp,
    const float* __restrict__ Z1,  const float* __restrict__ Z2,
    const float* __restrict__ W0,  const float* __restrict__ b0,
    const float* __restrict__ W1,  const float* __restrict__ b1,
    const float* __restrict__ W2,  const float* __restrict__ b2,
    float* __restrict__ out, float* __restrict__ ws, int use_ws)
{
    const int tid  = threadIdx.x;
    const int wave = tid >> 6;                      // 0..7
    const int lane = tid & 63;
    const int q    = lane >> 4;
    const int nh   = lane & 15;
    const int t    = wave >> 1;                     // tile 0..3
    const int role = wave & 1;                      // 0: nets 0/2, 1: nets 1/3
    const int path = blockIdx.x;                    // one path per block
    const int row  = t * 16 + nh;                   // this lane's option row

    __shared__ float4 w0t4[4 * 72];                 // k*(w_S,w_V,w_t, b0+rf*w_rf)
    __shared__ uint4  w1f[2048];                    // k*W1 bf16 frags, 32 KB
    __shared__ __align__(16) float b1k[4 * 64];     // k*b1, f32
    __shared__ float  fx[2][64];                    // phase-1 exchange [role][row]
    __shared__ float  gx[2][64];                    // phase-2 exchange

    const float rf = rfp[0];

    // ---- one-time staging: W0 columns + b1 (pre-scaled by TANH_K) ----
    if (tid < 256) {
        const int net = tid >> 6, kk = tid & 63;
        const float wsv = W0[net * 256 + 0 * 64 + kk];
        const float wvv = W0[net * 256 + 1 * 64 + kk];
        const float wrv = W0[net * 256 + 2 * 64 + kk];
        const float wtv = W0[net * 256 + 3 * 64 + kk];
        w0t4[net * 72 + kk + (kk >> 3)] =
            make_float4(TANH_K * wsv, TANH_K * wvv, TANH_K * wtv,
                        TANH_K * fmaf(rf, wrv, b0[net * 64 + kk]));
        b1k[tid] = TANH_K * b1[tid];
    }

    // ---- one-time staging: k*W1 -> LDS bf16 B-fragments ----
    // frag f: nh=f&15, q=(f>>4)&3, kh=(f>>6)&1, nt=(f>>7)&3, net=(f>>9)&3
#pragma unroll
    for (int it = 0; it < 4; ++it) {
        const int f   = it * 512 + tid;
        const int fnh = f & 15;
        const int fq  = (f >> 4) & 3;
        const int fkh = (f >> 6) & 1;
        const int fnt = (f >> 7) & 3;
        const int fnet= (f >> 9) & 3;
        const float* wp = W1 + fnet * 4096 + (fkh * 32 + fq * 8) * 64 + fnt * 16 + fnh;
        bf16x8 fr;
#pragma unroll
        for (int j = 0; j < 8; ++j) fr[j] = f2bf(TANH_K * wp[j * 64]);
        w1f[f] = __builtin_bit_cast(uint4, fr);
    }

    // ---- per-lane constants (only this wave's two nets) ----
    const float dta  = Tp[row] * (1.0f / N_STEPS);
    const float sqdt = sqrtf(dta);
    const int netA = role;                          // phase-1 net
    const int netB = role + 2;                      // phase-2 net

    float w2vA[4][4], w2vB[4][4];                   // [nt][r] at hid=16nt+4q+r
#pragma unroll
    for (int nt = 0; nt < 4; ++nt)
#pragma unroll
        for (int r = 0; r < 4; ++r) {
            const int hid = nt * 16 + 4 * q + r;
            w2vA[nt][r] = W2[netA * 64 + hid];
            w2vB[nt][r] = W2[netB * 64 + hid];
        }
    const float b2A = b2[netA], b2B = b2[netB];

    float Sreg = S0p[row];                          // register-carried state
    float Vreg = 0.2f;

    __syncthreads();

    const uint4* __restrict__ w1p = &w1f[q * 16 + nh];  // lane-contiguous base
    const float* __restrict__ z1p = Z1 + path * N_STEPS;
    const float* __restrict__ z2p = Z2 + path * N_STEPS;

    for (int step = 0; step < N_STEPS; ++step) {
        const float z1 = z1p[step];
        const float z2 = z2p[step];
        const float tA = dta * (float)step;

        // ---- phase 1: my net (role) on (S, V, rf, t) ----
        const float f = mlp_one(netA, q, nh, Sreg, Vreg, tA, w0t4, w1p, b1k, w2vA, b2A);
        if (q == 0) fx[role][row] = f;
        __syncthreads();
        {   // both waves update S redundantly (deterministic, same inputs)
            const float f0r = fx[0][row];
            const float f1r = fx[1][row];
            Sreg = Sreg * fmaf(f1r, z1, fmaf(f0r, dta, 1.0f));
        }

        // ---- phase 2: my net (role+2) on (S_new, V, rf, t) ----
        const float g = mlp_one(netB, q, nh, Sreg, Vreg, tA, w0t4, w1p, b1k, w2vB, b2B);
        if (q == 0) gx[role][row] = g;
        __syncthreads();
        {
            const float g2r = gx[0][row];
            const float g3r = gx[1][row];
            Vreg = Vreg * fmaf(g3r, sqdt * z2, fmaf(g2r, dta, 1.0f));
        }
    }

    // ---- payoff: one lane per row writes (no extra barrier needed) ----
    if (role == 0 && q == 0) {
        const float Tt   = dta * (float)N_STEPS;
        const float disc = __builtin_amdgcn_exp2f(-rf * Tt * 1.4426950408889634f)
                           * (1.0f / (float)N_PATHS);
        const float Kv = Kp[row];
        const float p1 = (Sreg - Kv < 0.0f) ? 0.0f : Sreg;
        const float v  = disc * p1;
        if (use_ws) ws[path * 64 + row] = v;
        else        atomicAdd(&out[row], v);
    }
}

__global__ void reduce_kernel(const float* __restrict__ ws, float* __restrict__ out) {
    __shared__ float acc[4][64];
    const int o = threadIdx.x & 63, g = threadIdx.x >> 6;
    float s = 0.0f;
    for (int b = g; b < N_PATHS; b += 4) s += ws[b * 64 + o];
    acc[g][o] = s;
    __syncthreads();
    if (threadIdx.x < 64)
        out[threadIdx.x] = acc[0][threadIdx.x] + acc[1][threadIdx.x]
                         + acc[2][threadIdx.x] + acc[3][threadIdx.x];
}

__global__ void zero_out_kernel(float* __restrict__ out) {
    out[threadIdx.x] = 0.0f;
}

extern "C" void kernel_launch(void* const* d_in, const int* in_sizes, int n_in,
                              void* d_out, int out_size, void* d_ws, size_t ws_size,
                              hipStream_t stream) {
    const float* S0p = (const float*)d_in[0];
    const float* Kp  = (const float*)d_in[1];
    const float* Tp  = (const float*)d_in[2];
    const float* rfp = (const float*)d_in[3];
    const float* Z1  = (const float*)d_in[4];
    const float* Z2  = (const float*)d_in[5];
    const float* W0  = (const float*)d_in[6];
    const float* b0  = (const float*)d_in[7];
    const float* W1  = (const float*)d_in[8];
    const float* b1  = (const float*)d_in[9];
    const float* W2  = (const float*)d_in[10];
    const float* b2  = (const float*)d_in[11];
    float* out = (float*)d_out;
    float* wsf = (float*)d_ws;

    const int use_ws = (ws_size >= (size_t)(N_PATHS * 64 * sizeof(float))) ? 1 : 0;

    if (!use_ws) zero_out_kernel<<<1, B_OPTS, 0, stream>>>(out);
    nsde_kernel<<<N_PATHS, 512, 0, stream>>>(S0p, Kp, Tp, rfp, Z1, Z2,
                                             W0, b0, W1, b1, W2, b2, out, wsf, use_ws);
    if (use_ws) reduce_kernel<<<1, 256, 0, stream>>>(wsf, out);
}

// Round 12
// 243.799 us; speedup vs baseline: 2.8555x; 1.0101x over previous
//
#include <hip/hip_runtime.h>

// NSDE pricer, R14: bisect completion — R11 + value-identical tweaks only.
// R12 (r-form + pk_fma + hoist/float2) NaN'd; R13 (r-form + hoist/float2,
// NO pk_fma) also NaN'd -> pk_fma exonerated; shared suspects = r-form vs
// hoist/float2. R14 drops the r-form entirely (back to R11's verified
// tanh_from_scaled, k*W1 frags, b1k=k*b1, w2v dot) and keeps ONLY:
//  (a) 8 W1-frag ds_reads hoisted above layer1 (latency under trans ops),
//  (b) fx/gx exchange as float2 (1 ds_read_b64 instead of 2 b32).
// Both are value-identical data movement. Pass -> r-form isolated as the NaN
// source (abandon it); NaN -> hoist/float2 implicated (revert to exact R11).
// Geometry/structure identical to R11 (165 us, passed): block 512 = 8 waves
// = 1 path (net-split pairs), grid 512, swapped MFMA (lane-local layer3,
// 2-shfl reduce), S/V register-carried, 2 barriers/step, anti-LICM asm
// barrier (R8), k=2/ln2 folded into weights (R10), waves_per_eu(4).

#define N_PATHS 512
#define N_STEPS 32
#define B_OPTS  64
#define HID     64

#define TANH_K 2.8853900817779268f   // 2/ln2: tanh(x) = 1 - 2/(2^(k*x)+1)

typedef __attribute__((ext_vector_type(8))) short bf16x8;   // 8 bf16 (4 VGPRs)
typedef __attribute__((ext_vector_type(4))) float f32x4;
typedef __attribute__((ext_vector_type(4))) unsigned u32x4;

__device__ __forceinline__ float tanh_from_scaled(float a) {
    // a = k*x already (k folded into weights). tanh = 1 - 2/(2^a + 1).
    float u = __builtin_amdgcn_exp2f(a);
    float r = __builtin_amdgcn_rcpf(u + 1.0f);
    return fmaf(-2.0f, r, 1.0f);
}

__device__ __forceinline__ short f2bf(float f) {            // fp32 -> bf16 RNE
    union { float f; unsigned u; } c; c.f = f;
    unsigned u = c.u + 0x7FFFu + ((c.u >> 16) & 1u);
    return (short)(u >> 16);
}

__device__ __forceinline__ unsigned cvt_pk_bf16(float lo, float hi) {
    // packs lo -> [15:0], hi -> [31:16] as bf16 (RNE), single VALU op.
    unsigned r;
    asm("v_cvt_pk_bf16_f32 %0, %1, %2" : "=v"(r) : "v"(lo), "v"(hi));
    return r;
}

// One net (swapped MFMA): layer1 scalar chain -> tanh bf16; layer2
// MFMA(A=k*W1 frags, B=h1, C=k*b1); layer3 lane-local tanh-dot + 2-shfl
// reduce. Returns f for row nh, valid at ALL lanes.
__device__ __forceinline__ float mlp_one(
    int net, int q, int nh,
    float Sa, float Va, float tA,
    const float4* __restrict__ w0t4,            // LDS, [4][72] swizzled, k-scaled
    const uint4*  __restrict__ w1p,             // LDS frags (k*W1), lane-offset
    const float*  __restrict__ b1k,             // LDS, k*b1, [4][64]
    const float (&w2v)[4][4], float b2s)        // [nt][r] = W2[net*64+16nt+4q+r]
{
    // Block LICM: nothing memory-derived carried across phases/steps
    // (R5/R7 lesson: hoisted LDS values spill to scratch -> 1.7 GB HBM).
    asm volatile("" ::: "memory");
    // ---- W1 frags early: DS latency hides under layer1's trans ops ----
    uint4 wfr[8];
#pragma unroll
    for (int i = 0; i < 8; ++i) wfr[i] = w1p[(net * 8 + i) * 64];

    // ---- layer1: lane holds h1[row=nh][k=32kh+8q+j] as bf16 ----
    u32x4 afr[2];                                // [kh], 8 bf16 each
#pragma unroll
    for (int kh = 0; kh < 2; ++kh) {
        float tv[8];
#pragma unroll
        for (int j = 0; j < 8; ++j) {
            const int kk = kh * 32 + q * 8 + j;
            const float4 w = w0t4[net * 72 + kk + (kk >> 3)]; // bank-swizzled
            const float a = fmaf(Sa, w.x, fmaf(Va, w.y, fmaf(tA, w.z, w.w)));
            tv[j] = tanh_from_scaled(a);         // w pre-scaled by k
        }
#pragma unroll
        for (int d = 0; d < 4; ++d)
            afr[kh][d] = cvt_pk_bf16(tv[2 * d], tv[2 * d + 1]);
    }
    const bf16x8 h0 = __builtin_bit_cast(bf16x8, afr[0]);
    const bf16x8 h1 = __builtin_bit_cast(bf16x8, afr[1]);

    // ---- layer2+3: C[m=4q+r][n=nh] = h2[row=nh][hid=16nt+4q+r] ----
    float s = 0.0f;
#pragma unroll
    for (int nt = 0; nt < 4; ++nt) {
        f32x4 c = *(const f32x4*)&b1k[net * 64 + nt * 16 + 4 * q];  // b128 bcast
        c = __builtin_amdgcn_mfma_f32_16x16x32_bf16(
                __builtin_bit_cast(bf16x8, wfr[nt * 2 + 0]), h0, c, 0, 0, 0);
        c = __builtin_amdgcn_mfma_f32_16x16x32_bf16(
                __builtin_bit_cast(bf16x8, wfr[nt * 2 + 1]), h1, c, 0, 0, 0);
#pragma unroll
        for (int r = 0; r < 4; ++r)
            s = fmaf(tanh_from_scaled(c[r]), w2v[nt][r], s);
    }
    s += __shfl_xor(s, 16);                      // reduce over q-groups
    s += __shfl_xor(s, 32);
    return s + b2s;
}

__global__ __launch_bounds__(512)
__attribute__((amdgpu_waves_per_eu(4)))
void nsde_kernel(
    const float* __restrict__ S0p, const float* __restrict__ Kp,
    const float* __restrict__ Tp,  const float* __restrict__ rfp,
    const float* __restrict__ Z1,  const float* __restrict__ Z2,
    const float* __restrict__ W0,  const float* __restrict__ b0,
    const float* __restrict__ W1,  const float* __restrict__ b1,
    const float* __restrict__ W2,  const float* __restrict__ b2,
    float* __restrict__ out, float* __restrict__ ws, int use_ws)
{
    const int tid  = threadIdx.x;
    const int wave = tid >> 6;                      // 0..7
    const int lane = tid & 63;
    const int q    = lane >> 4;
    const int nh   = lane & 15;
    const int t    = wave >> 1;                     // tile 0..3
    const int role = wave & 1;                      // 0: nets 0/2, 1: nets 1/3
    const int path = blockIdx.x;                    // one path per block
    const int row  = t * 16 + nh;                   // this lane's option row

    __shared__ float4 w0t4[4 * 72];                 // k*(w_S,w_V,w_t, b0+rf*w_rf)
    __shared__ uint4  w1f[2048];                    // k*W1 bf16 frags, 32 KB
    __shared__ __align__(16) float b1k[4 * 64];     // k*b1, f32
    __shared__ float2 fx2[64];                      // phase-1 exchange [row]
    __shared__ float2 gx2[64];                      // phase-2 exchange

    const float rf = rfp[0];

    // ---- one-time staging: W0 columns + b1 (pre-scaled by TANH_K) ----
    if (tid < 256) {
        const int net = tid >> 6, kk = tid & 63;
        const float wsv = W0[net * 256 + 0 * 64 + kk];
        const float wvv = W0[net * 256 + 1 * 64 + kk];
        const float wrv = W0[net * 256 + 2 * 64 + kk];
        const float wtv = W0[net * 256 + 3 * 64 + kk];
        w0t4[net * 72 + kk + (kk >> 3)] =
            make_float4(TANH_K * wsv, TANH_K * wvv, TANH_K * wtv,
                        TANH_K * fmaf(rf, wrv, b0[net * 64 + kk]));
        b1k[tid] = TANH_K * b1[tid];
    }

    // ---- one-time staging: k*W1 -> LDS bf16 B-fragments ----
    // frag f: nh=f&15, q=(f>>4)&3, kh=(f>>6)&1, nt=(f>>7)&3, net=(f>>9)&3
#pragma unroll
    for (int it = 0; it < 4; ++it) {
        const int f   = it * 512 + tid;
        const int fnh = f & 15;
        const int fq  = (f >> 4) & 3;
        const int fkh = (f >> 6) & 1;
        const int fnt = (f >> 7) & 3;
        const int fnet= (f >> 9) & 3;
        const float* wp = W1 + fnet * 4096 + (fkh * 32 + fq * 8) * 64 + fnt * 16 + fnh;
        bf16x8 fr;
#pragma unroll
        for (int j = 0; j < 8; ++j) fr[j] = f2bf(TANH_K * wp[j * 64]);
        w1f[f] = __builtin_bit_cast(uint4, fr);
    }

    // ---- per-lane constants (only this wave's two nets) ----
    const float dta  = Tp[row] * (1.0f / N_STEPS);
    const float sqdt = sqrtf(dta);
    const int netA = role;                          // phase-1 net
    const int netB = role + 2;                      // phase-2 net

    float w2vA[4][4], w2vB[4][4];                   // [nt][r] at hid=16nt+4q+r
#pragma unroll
    for (int nt = 0; nt < 4; ++nt)
#pragma unroll
        for (int r = 0; r < 4; ++r) {
            const int hid = nt * 16 + 4 * q + r;
            w2vA[nt][r] = W2[netA * 64 + hid];
            w2vB[nt][r] = W2[netB * 64 + hid];
        }
    const float b2A = b2[netA], b2B = b2[netB];

    float Sreg = S0p[row];                          // register-carried state
    float Vreg = 0.2f;

    __syncthreads();

    const uint4* __restrict__ w1p = &w1f[q * 16 + nh];  // lane-contiguous base
    const float* __restrict__ z1p = Z1 + path * N_STEPS;
    const float* __restrict__ z2p = Z2 + path * N_STEPS;

    for (int step = 0; step < N_STEPS; ++step) {
        const float z1 = z1p[step];
        const float z2 = z2p[step];
        const float tA = dta * (float)step;

        // ---- phase 1: my net (role) on (S, V, rf, t) ----
        const float f = mlp_one(netA, q, nh, Sreg, Vreg, tA,
                                w0t4, w1p, b1k, w2vA, b2A);
        if (q == 0) { if (role == 0) fx2[row].x = f; else fx2[row].y = f; }
        __syncthreads();
        {   // both waves update S redundantly (deterministic, same inputs)
            const float2 fp = fx2[row];
            Sreg = Sreg * fmaf(fp.y, z1, fmaf(fp.x, dta, 1.0f));
        }

        // ---- phase 2: my net (role+2) on (S_new, V, rf, t) ----
        const float g = mlp_one(netB, q, nh, Sreg, Vreg, tA,
                                w0t4, w1p, b1k, w2vB, b2B);
        if (q == 0) { if (role == 0) gx2[row].x = g; else gx2[row].y = g; }
        __syncthreads();
        {
            const float2 gp = gx2[row];
            Vreg = Vreg * fmaf(gp.y, sqdt * z2, fmaf(gp.x, dta, 1.0f));
        }
    }

    // ---- payoff: one lane per row writes (no extra barrier needed) ----
    if (role == 0 && q == 0) {
        const float Tt   = dta * (float)N_STEPS;
        const float disc = __builtin_amdgcn_exp2f(-rf * Tt * 1.4426950408889634f)
                           * (1.0f / (float)N_PATHS);
        const float Kv = Kp[row];
        const float p1 = (Sreg - Kv < 0.0f) ? 0.0f : Sreg;
        const float v  = disc * p1;
        if (use_ws) ws[path * 64 + row] = v;
        else        atomicAdd(&out[row], v);
    }
}

__global__ void reduce_kernel(const float* __restrict__ ws, float* __restrict__ out) {
    __shared__ float acc[4][64];
    const int o = threadIdx.x & 63, g = threadIdx.x >> 6;
    float s = 0.0f;
    for (int b = g; b < N_PATHS; b += 4) s += ws[b * 64 + o];
    acc[g][o] = s;
    __syncthreads();
    if (threadIdx.x < 64)
        out[threadIdx.x] = acc[0][threadIdx.x] + acc[1][threadIdx.x]
                         + acc[2][threadIdx.x] + acc[3][threadIdx.x];
}

__global__ void zero_out_kernel(float* __restrict__ out) {
    out[threadIdx.x] = 0.0f;
}

extern "C" void kernel_launch(void* const* d_in, const int* in_sizes, int n_in,
                              void* d_out, int out_size, void* d_ws, size_t ws_size,
                              hipStream_t stream) {
    const float* S0p = (const float*)d_in[0];
    const float* Kp  = (const float*)d_in[1];
    const float* Tp  = (const float*)d_in[2];
    const float* rfp = (const float*)d_in[3];
    const float* Z1  = (const float*)d_in[4];
    const float* Z2  = (const float*)d_in[5];
    const float* W0  = (const float*)d_in[6];
    const float* b0  = (const float*)d_in[7];
    const float* W1  = (const float*)d_in[8];
    const float* b1  = (const float*)d_in[9];
    const float* W2  = (const float*)d_in[10];
    const float* b2  = (const float*)d_in[11];
    float* out = (float*)d_out;
    float* wsf = (float*)d_ws;

    const int use_ws = (ws_size >= (size_t)(N_PATHS * 64 * sizeof(float))) ? 1 : 0;

    if (!use_ws) zero_out_kernel<<<1, B_OPTS, 0, stream>>>(out);
    nsde_kernel<<<N_PATHS, 512, 0, stream>>>(S0p, Kp, Tp, rfp, Z1, Z2,
                                             W0, b0, W1, b1, W2, b2, out, wsf, use_ws);
    if (use_ws) reduce_kernel<<<1, 256, 0, stream>>>(wsf, out);
}

// Round 13
// 240.747 us; speedup vs baseline: 2.8917x; 1.0127x over previous
//
#include <hip/hip_runtime.h>

// NSDE pricer, R15: layer1 via MFMA (sigma-permuted hidden) on the R14 base.
// R14: 164.5 us, VALUBusy 80%, MfmaUtil 9%, occ 36% (grid-limited 16 w/CU),
// VGPR 48. tanh trans chains (~960 cyc/mlp_one) are the algorithmic floor;
// the big removable block is layer1's 48 fma + 16 LDS reads (~96 VALU cyc).
// Move it to the idle MFMA pipe:
//  - MFMA-1 per 16-hidden tile mt: C[m=4q+r][n=nh] = preact of hidden
//    H = 16mt+4q+r, row nh. A = W0 frag (slots: wShi,wShi,wSlo,wV,wThi,
//    wThi,wTlo,0 at q=0), B = input frag (Shi,Slo | Shi,V | thi,tlo | thi,0
//    at q=0; zero elsewhere), C-init = k*(b0 + rf*w_rf) fp32 from LDS.
//    Double-bf16 split for S and w_S/w_t keeps the big terms fp32-accurate
//    (bf16xbf16 products are exact in the fp32 accumulator).
//  - sigma trick: layer2's k-slot for hidden H is chosen as
//    k = 32*(mt>>1) + 8q + 4*(mt&1) + r, so MFMA-1 output feeds MFMA-2's
//    B-frag with ZERO cross-lane moves: afr[x] = pack(tanh(c1[2x][0..3]),
//    tanh(c1[2x+1][0..3])). Only W1 staging's k-index formula changes.
// NO numeric-identity changes to tanh (R12/R13 NaN lesson): exact
// tanh_from_scaled kept. Geometry unchanged: block 512 = 8 waves = 1 path
// (net-split pairs), grid 512, swapped MFMA layer2, S/V register-carried,
// 2 barriers/step, anti-LICM asm barrier (R8), k=2/ln2 in weights (R10),
// waves_per_eu(4).

#define N_PATHS 512
#define N_STEPS 32
#define B_OPTS  64
#define HID     64

#define TANH_K 2.8853900817779268f   // 2/ln2: tanh(x) = 1 - 2/(2^(k*x)+1)

typedef __attribute__((ext_vector_type(8))) short bf16x8;   // 8 bf16 (4 VGPRs)
typedef __attribute__((ext_vector_type(4))) float f32x4;
typedef __attribute__((ext_vector_type(4))) unsigned u32x4;

__device__ __forceinline__ float tanh_from_scaled(float a) {
    // a = k*x already (k folded into weights). tanh = 1 - 2/(2^a + 1).
    float u = __builtin_amdgcn_exp2f(a);
    float r = __builtin_amdgcn_rcpf(u + 1.0f);
    return fmaf(-2.0f, r, 1.0f);
}

__device__ __forceinline__ short f2bf(float f) {            // fp32 -> bf16 RNE
    union { float f; unsigned u; } c; c.f = f;
    unsigned u = c.u + 0x7FFFu + ((c.u >> 16) & 1u);
    return (short)(u >> 16);
}

__device__ __forceinline__ unsigned cvt_pk_bf16(float lo, float hi) {
    // packs lo -> [15:0], hi -> [31:16] as bf16 (RNE), single VALU op.
    unsigned r;
    asm("v_cvt_pk_bf16_f32 %0, %1, %2" : "=v"(r) : "v"(lo), "v"(hi));
    return r;
}

__device__ __forceinline__ void bsplit(float x, float& hi, float& lo) {
    // double-bf16 split: x = hi + lo with hi = bf16(x) (as fp32), lo residual.
    const unsigned u = cvt_pk_bf16(x, x);
    hi = __builtin_bit_cast(float, u << 16);
    lo = x - hi;
}

// One net: layer1 via MFMA-1 (4 tiles) + tanh + pack; layer2 MFMA-2
// (A=k*W1 sigma-frags, B=h1, C=k*b1); layer3 lane-local tanh-dot + 2-shfl
// reduce. Returns f for row nh, valid at ALL lanes.
__device__ __forceinline__ float mlp_one(
    int net, int q,
    bf16x8 svt,                                 // input frag (q-masked by caller)
    const uint4*  __restrict__ w0ap,            // LDS W0 A-frags, lane-offset
    const float*  __restrict__ b0e,             // LDS, k*(b0+rf*w_rf), [4][64]
    const uint4*  __restrict__ w1p,             // LDS W1 frags (k*W1), lane-offset
    const float*  __restrict__ b1k,             // LDS, k*b1, [4][64]
    const float (&w2v)[4][4], float b2s)        // [nt][r] = W2[net*64+16nt+4q+r]
{
    // Block LICM: nothing memory-derived carried across phases/steps
    // (R5/R7 lesson: hoisted LDS values spill to scratch -> 1.7 GB HBM).
    asm volatile("" ::: "memory");
    // ---- frag loads early: DS latency hides under MFMA/trans ----
    uint4 wfr[8];
#pragma unroll
    for (int i = 0; i < 8; ++i) wfr[i] = w1p[(net * 8 + i) * 64];
    uint4 w0f[4];
#pragma unroll
    for (int mt = 0; mt < 4; ++mt) w0f[mt] = w0ap[(net * 4 + mt) * 64];

    // ---- layer1 (MFMA pipe): preact[H=16mt+4q+r][row=nh] ----
    f32x4 c1[4];
#pragma unroll
    for (int mt = 0; mt < 4; ++mt) {
        f32x4 ci = *(const f32x4*)&b0e[net * 64 + mt * 16 + 4 * q];
        c1[mt] = __builtin_amdgcn_mfma_f32_16x16x32_bf16(
                     __builtin_bit_cast(bf16x8, w0f[mt]), svt, ci, 0, 0, 0);
    }
    // ---- tanh + pack directly into MFMA-2 B-frag order (sigma trick) ----
    u32x4 afr[2];
#pragma unroll
    for (int x = 0; x < 2; ++x) {
        afr[x][0] = cvt_pk_bf16(tanh_from_scaled(c1[2 * x][0]),
                                tanh_from_scaled(c1[2 * x][1]));
        afr[x][1] = cvt_pk_bf16(tanh_from_scaled(c1[2 * x][2]),
                                tanh_from_scaled(c1[2 * x][3]));
        afr[x][2] = cvt_pk_bf16(tanh_from_scaled(c1[2 * x + 1][0]),
                                tanh_from_scaled(c1[2 * x + 1][1]));
        afr[x][3] = cvt_pk_bf16(tanh_from_scaled(c1[2 * x + 1][2]),
                                tanh_from_scaled(c1[2 * x + 1][3]));
    }
    const bf16x8 h0 = __builtin_bit_cast(bf16x8, afr[0]);
    const bf16x8 h1 = __builtin_bit_cast(bf16x8, afr[1]);

    // ---- layer2+3: C[m=4q+r][n=nh] = h2[row=nh][hid2=16nt+4q+r] ----
    float s = 0.0f;
#pragma unroll
    for (int nt = 0; nt < 4; ++nt) {
        f32x4 c = *(const f32x4*)&b1k[net * 64 + nt * 16 + 4 * q];  // b128 bcast
        c = __builtin_amdgcn_mfma_f32_16x16x32_bf16(
                __builtin_bit_cast(bf16x8, wfr[nt * 2 + 0]), h0, c, 0, 0, 0);
        c = __builtin_amdgcn_mfma_f32_16x16x32_bf16(
                __builtin_bit_cast(bf16x8, wfr[nt * 2 + 1]), h1, c, 0, 0, 0);
#pragma unroll
        for (int r = 0; r < 4; ++r)
            s = fmaf(tanh_from_scaled(c[r]), w2v[nt][r], s);
    }
    s += __shfl_xor(s, 16);                      // reduce over q-groups
    s += __shfl_xor(s, 32);
    return s + b2s;
}

__global__ __launch_bounds__(512)
__attribute__((amdgpu_waves_per_eu(4)))
void nsde_kernel(
    const float* __restrict__ S0p, const float* __restrict__ Kp,
    const float* __restrict__ Tp,  const float* __restrict__ rfp,
    const float* __restrict__ Z1,  const float* __restrict__ Z2,
    const float* __restrict__ W0,  const float* __restrict__ b0,
    const float* __restrict__ W1,  const float* __restrict__ b1,
    const float* __restrict__ W2,  const float* __restrict__ b2,
    float* __restrict__ out, float* __restrict__ ws, int use_ws)
{
    const int tid  = threadIdx.x;
    const int wave = tid >> 6;                      // 0..7
    const int lane = tid & 63;
    const int q    = lane >> 4;
    const int nh   = lane & 15;
    const int t    = wave >> 1;                     // tile 0..3
    const int role = wave & 1;                      // 0: nets 0/2, 1: nets 1/3
    const int path = blockIdx.x;                    // one path per block
    const int row  = t * 16 + nh;                   // this lane's option row

    __shared__ uint4  w0a[1024];                    // W0 A-frags, 16 KB
    __shared__ uint4  w1f[2048];                    // k*W1 bf16 frags, 32 KB
    __shared__ __align__(16) float b0e[4 * 64];     // k*(b0 + rf*w_rf), f32
    __shared__ __align__(16) float b1k[4 * 64];     // k*b1, f32
    __shared__ float2 fx2[64];                      // phase-1 exchange [row]
    __shared__ float2 gx2[64];                      // phase-2 exchange

    const float rf = rfp[0];

    // ---- one-time staging: b0e, b1k ----
    if (tid < 256) {
        const int net = tid >> 6, kk = tid & 63;
        b0e[tid] = TANH_K * fmaf(rf, W0[net * 256 + 128 + kk], b0[tid]);
        b1k[tid] = TANH_K * b1[tid];
    }

    // ---- one-time staging: W0 A-frags (double-bf16 wS, wT; single wV) ----
    // frag (net,mt) lane(q0,nh0): q0==0 slots: wShi,wShi | wSlo,wV | wThi,wThi
    // | wTlo,0 for hidden H = 16mt + nh0; all other lanes zero.
#pragma unroll
    for (int it = 0; it < 2; ++it) {
        const int f   = it * 512 + tid;             // 0..1023
        const int ls  = f & 63;
        const int mt  = (f >> 6) & 3;
        const int nts = f >> 8;                     // net
        uint4 fr = {0u, 0u, 0u, 0u};
        if ((ls >> 4) == 0) {
            const int H = mt * 16 + (ls & 15);
            const float wS = TANH_K * W0[nts * 256 + 0   + H];
            const float wV = TANH_K * W0[nts * 256 + 64  + H];
            const float wT = TANH_K * W0[nts * 256 + 192 + H];
            const unsigned sh = (unsigned)(unsigned short)f2bf(wS);
            const float shf   = __builtin_bit_cast(float, sh << 16);
            const unsigned th = (unsigned)(unsigned short)f2bf(wT);
            const float thf   = __builtin_bit_cast(float, th << 16);
            fr.x = sh | (sh << 16);
            fr.y = (unsigned)(unsigned short)f2bf(wS - shf)
                 | ((unsigned)(unsigned short)f2bf(wV) << 16);
            fr.z = th | (th << 16);
            fr.w = (unsigned)(unsigned short)f2bf(wT - thf);
        }
        w0a[f] = fr;
    }

    // ---- one-time staging: k*W1 -> LDS bf16 frags, sigma k-ordering ----
    // frag f: nh=f&15, q=(f>>4)&3, kh=(f>>6)&1, nt=(f>>7)&3, net=(f>>9)&3
    // element j holds k*W1[H = 16*(2kh + (j>>2)) + 4q + (j&3)][16nt + nh].
#pragma unroll
    for (int it = 0; it < 4; ++it) {
        const int f   = it * 512 + tid;
        const int fnh = f & 15;
        const int fq  = (f >> 4) & 3;
        const int fkh = (f >> 6) & 1;
        const int fnt = (f >> 7) & 3;
        const int fnet= (f >> 9) & 3;
        bf16x8 fr;
#pragma unroll
        for (int j = 0; j < 8; ++j) {
            const int H = 16 * (2 * fkh + (j >> 2)) + 4 * fq + (j & 3);
            fr[j] = f2bf(TANH_K * W1[fnet * 4096 + H * 64 + fnt * 16 + fnh]);
        }
        w1f[f] = __builtin_bit_cast(uint4, fr);
    }

    // ---- per-lane constants (only this wave's two nets) ----
    const float dta  = Tp[row] * (1.0f / N_STEPS);
    const float sqdt = sqrtf(dta);
    const int netA = role;                          // phase-1 net
    const int netB = role + 2;                      // phase-2 net

    float w2vA[4][4], w2vB[4][4];                   // [nt][r] at hid=16nt+4q+r
#pragma unroll
    for (int nt = 0; nt < 4; ++nt)
#pragma unroll
        for (int r = 0; r < 4; ++r) {
            const int hid = nt * 16 + 4 * q + r;
            w2vA[nt][r] = W2[netA * 64 + hid];
            w2vB[nt][r] = W2[netB * 64 + hid];
        }
    const float b2A = b2[netA], b2B = b2[netB];

    float Sreg = S0p[row];                          // register-carried state
    float Vreg = 0.2f;

    __syncthreads();

    const uint4* __restrict__ w0ap = &w0a[lane];    // lane-contiguous bases
    const uint4* __restrict__ w1p  = &w1f[lane];
    const float* __restrict__ z1p  = Z1 + path * N_STEPS;
    const float* __restrict__ z2p  = Z2 + path * N_STEPS;
    const bool q0 = (q == 0);

    for (int step = 0; step < N_STEPS; ++step) {
        const float z1 = z1p[step];
        const float z2 = z2p[step];
        const float tA = dta * (float)step;

        // per-step input-frag parts (shared by both phases)
        float th, tl; bsplit(tA, th, tl);
        const unsigned td2 = cvt_pk_bf16(th, tl);
        const unsigned td3 = cvt_pk_bf16(th, 0.0f);

        // ---- phase 1: my net (role) on (S, V, rf, t) ----
        {
            float sh, sl; bsplit(Sreg, sh, sl);
            u32x4 sv;
            sv[0] = q0 ? cvt_pk_bf16(sh, sl)   : 0u;
            sv[1] = q0 ? cvt_pk_bf16(sh, Vreg) : 0u;
            sv[2] = q0 ? td2 : 0u;
            sv[3] = q0 ? td3 : 0u;
            const float f = mlp_one(netA, q, __builtin_bit_cast(bf16x8, sv),
                                    w0ap, b0e, w1p, b1k, w2vA, b2A);
            if (q0) { if (role == 0) fx2[row].x = f; else fx2[row].y = f; }
        }
        __syncthreads();
        {   // both waves update S redundantly (deterministic, same inputs)
            const float2 fp = fx2[row];
            Sreg = Sreg * fmaf(fp.y, z1, fmaf(fp.x, dta, 1.0f));
        }

        // ---- phase 2: my net (role+2) on (S_new, V, rf, t) ----
        {
            float sh, sl; bsplit(Sreg, sh, sl);
            u32x4 sv;
            sv[0] = q0 ? cvt_pk_bf16(sh, sl)   : 0u;
            sv[1] = q0 ? cvt_pk_bf16(sh, Vreg) : 0u;
            sv[2] = q0 ? td2 : 0u;
            sv[3] = q0 ? td3 : 0u;
            const float g = mlp_one(netB, q, __builtin_bit_cast(bf16x8, sv),
                                    w0ap, b0e, w1p, b1k, w2vB, b2B);
            if (q0) { if (role == 0) gx2[row].x = g; else gx2[row].y = g; }
        }
        __syncthreads();
        {
            const float2 gp = gx2[row];
            Vreg = Vreg * fmaf(gp.y, sqdt * z2, fmaf(gp.x, dta, 1.0f));
        }
    }

    // ---- payoff: one lane per row writes (no extra barrier needed) ----
    if (role == 0 && q == 0) {
        const float Tt   = dta * (float)N_STEPS;
        const float disc = __builtin_amdgcn_exp2f(-rf * Tt * 1.4426950408889634f)
                           * (1.0f / (float)N_PATHS);
        const float Kv = Kp[row];
        const float p1 = (Sreg - Kv < 0.0f) ? 0.0f : Sreg;
        const float v  = disc * p1;
        if (use_ws) ws[path * 64 + row] = v;
        else        atomicAdd(&out[row], v);
    }
}

__global__ void reduce_kernel(const float* __restrict__ ws, float* __restrict__ out) {
    __shared__ float acc[4][64];
    const int o = threadIdx.x & 63, g = threadIdx.x >> 6;
    float s = 0.0f;
    for (int b = g; b < N_PATHS; b += 4) s += ws[b * 64 + o];
    acc[g][o] = s;
    __syncthreads();
    if (threadIdx.x < 64)
        out[threadIdx.x] = acc[0][threadIdx.x] + acc[1][threadIdx.x]
                         + acc[2][threadIdx.x] + acc[3][threadIdx.x];
}

__global__ void zero_out_kernel(float* __restrict__ out) {
    out[threadIdx.x] = 0.0f;
}

extern "C" void kernel_launch(void* const* d_in, const int* in_sizes, int n_in,
                              void* d_out, int out_size, void* d_ws, size_t ws_size,
                              hipStream_t stream) {
    const float* S0p = (const float*)d_in[0];
    const float* Kp  = (const float*)d_in[1];
    const float* Tp  = (const float*)d_in[2];
    const float* rfp = (const float*)d_in[3];
    const float* Z1  = (const float*)d_in[4];
    const float* Z2  = (const float*)d_in[5];
    const float* W0  = (const float*)d_in[6];
    const float* b0  = (const float*)d_in[7];
    const float* W1  = (const float*)d_in[8];
    const float* b1  = (const float*)d_in[9];
    const float* W2  = (const float*)d_in[10];
    const float* b2  = (const float*)d_in[11];
    float* out = (float*)d_out;
    float* wsf = (float*)d_ws;

    const int use_ws = (ws_size >= (size_t)(N_PATHS * 64 * sizeof(float))) ? 1 : 0;

    if (!use_ws) zero_out_kernel<<<1, B_OPTS, 0, stream>>>(out);
    nsde_kernel<<<N_PATHS, 512, 0, stream>>>(S0p, Kp, Tp, rfp, Z1, Z2,
                                             W0, b0, W1, b1, W2, b2, out, wsf, use_ws);
    if (use_ws) reduce_kernel<<<1, 256, 0, stream>>>(wsf, out);
}